// Round 1
// baseline (550.921 us; speedup 1.0000x reference)
//
#include <hip/hip_runtime.h>
#include <math.h>

#define VNUM 6890
#define JNUM 24
#define BNUM 1024
#define NBETA 10
#define K3 (3*VNUM)          // 20670
#define KTOT 217             // 10 shape + 207 pose rows
#define COEF_ROW 224         // padded coefficient row (K padded to 220, row to 224)
#define A_ROW 288            // 24 joints * 12 floats

// workspace layout (floats)
#define SJ_OFF   0                               // 24*33 = 792
#define COEF_OFF 1024                            // 1024*224
#define AW_OFF   (COEF_OFF + BNUM*COEF_ROW)      // 230400; size 1024*288
// total = 525312 floats ~ 2.1 MB

__constant__ int c_parents[24] = {-1,0,0,0,1,2,3,4,5,6,7,8,9,9,9,12,13,14,16,17,18,19,20,21};

// ---------------------------------------------------------------------------
// Kernel A: SJ[j][k][d] = sum_v dirs[k][v*3+d] * Jreg[v][j]   (k=10 -> v_template)
// ---------------------------------------------------------------------------
__global__ __launch_bounds__(256) void k_sj(const float* __restrict__ v_template,
                                            const float* __restrict__ shapedirs,
                                            const float* __restrict__ Jreg,
                                            float* __restrict__ ws) {
    const int j = blockIdx.x;          // 0..23
    const int tid = threadIdx.x;       // 0..255
    float acc[33];
#pragma unroll
    for (int i = 0; i < 33; ++i) acc[i] = 0.f;

    for (int v = tid; v < VNUM; v += 256) {
        const float jr = Jreg[v*JNUM + j];
#pragma unroll
        for (int d = 0; d < 3; ++d) acc[30+d] += v_template[v*3+d] * jr;
#pragma unroll
        for (int k = 0; k < NBETA; ++k) {
#pragma unroll
            for (int d = 0; d < 3; ++d)
                acc[k*3+d] += shapedirs[k*K3 + v*3 + d] * jr;
        }
    }
    // wave reduce (64-lane)
#pragma unroll
    for (int i = 0; i < 33; ++i) {
        for (int off = 32; off > 0; off >>= 1)
            acc[i] += __shfl_down(acc[i], off, 64);
    }
    __shared__ float red[4][33];
    const int lane = tid & 63, wv = tid >> 6;
    if (lane == 0) {
#pragma unroll
        for (int i = 0; i < 33; ++i) red[wv][i] = acc[i];
    }
    __syncthreads();
    if (tid < 33)
        ws[SJ_OFF + j*33 + tid] = red[0][tid] + red[1][tid] + red[2][tid] + red[3][tid];
}

// ---------------------------------------------------------------------------
// Kernel B: per-batch Rodrigues, joint locs, kinematic chain, A, coef row
// ---------------------------------------------------------------------------
__global__ __launch_bounds__(64) void k_batch(const float* __restrict__ shapes,
                                              const float* __restrict__ poses,
                                              float* __restrict__ ws) {
    const int b = blockIdx.x;
    const int j = threadIdx.x;
    __shared__ float sR[24][9];
    __shared__ float sJ[24][3];
    __shared__ float sG[24][12];

    float* coefT = ws + COEF_OFF + (size_t)b*COEF_ROW;
    float* Aw    = ws + AW_OFF   + (size_t)b*A_ROW;
    const float* SJ = ws + SJ_OFF;

    if (j < 24) {
        const float rx = poses[b*72 + j*3 + 0];
        const float ry = poses[b*72 + j*3 + 1];
        const float rz = poses[b*72 + j*3 + 2];
        const float t2 = rx*rx + ry*ry + rz*rz + 1e-8f;
        const float th = sqrtf(t2);
        const float iv = 1.f/th;
        const float ax = rx*iv, ay = ry*iv, az = rz*iv;
        const float s = sinf(th), c = cosf(th), o = 1.f - c;
        float K[9] = {0.f, -az, ay,  az, 0.f, -ax,  -ay, ax, 0.f};
        float R[9];
#pragma unroll
        for (int m = 0; m < 3; ++m)
#pragma unroll
            for (int n = 0; n < 3; ++n) {
                const float kk = K[m*3+0]*K[0+n] + K[m*3+1]*K[3+n] + K[m*3+2]*K[6+n];
                R[m*3+n] = ((m==n)?1.f:0.f) + s*K[m*3+n] + o*kk;
            }
#pragma unroll
        for (int e = 0; e < 9; ++e) sR[j][e] = R[e];
        if (j >= 1) {
#pragma unroll
            for (int e = 0; e < 9; ++e)
                coefT[10 + (j-1)*9 + e] = R[e] - ((e==0||e==4||e==8)?1.f:0.f);
        }
        // joint location
#pragma unroll
        for (int d = 0; d < 3; ++d) {
            float jl = SJ[j*33 + 30 + d];
#pragma unroll
            for (int k = 0; k < NBETA; ++k) jl += shapes[b*NBETA+k] * SJ[j*33 + k*3 + d];
            sJ[j][d] = jl;
        }
    }
    if (j < NBETA) coefT[j] = shapes[b*NBETA + j];
    if (j < 7)     coefT[KTOT + j] = 0.f;           // pad 217..223
    __syncthreads();

    if (j == 0) {
        // root
#pragma unroll
        for (int m = 0; m < 3; ++m) {
            sG[0][m*4+0] = sR[0][m*3+0];
            sG[0][m*4+1] = sR[0][m*3+1];
            sG[0][m*4+2] = sR[0][m*3+2];
            sG[0][m*4+3] = sJ[0][m];
        }
        for (int jj = 1; jj < 24; ++jj) {
            const int p = c_parents[jj];
            const float r0 = sJ[jj][0]-sJ[p][0];
            const float r1 = sJ[jj][1]-sJ[p][1];
            const float r2 = sJ[jj][2]-sJ[p][2];
            for (int m = 0; m < 3; ++m) {
                const float g0 = sG[p][m*4+0], g1 = sG[p][m*4+1], g2 = sG[p][m*4+2], gt = sG[p][m*4+3];
                sG[jj][m*4+0] = g0*sR[jj][0] + g1*sR[jj][3] + g2*sR[jj][6];
                sG[jj][m*4+1] = g0*sR[jj][1] + g1*sR[jj][4] + g2*sR[jj][7];
                sG[jj][m*4+2] = g0*sR[jj][2] + g1*sR[jj][5] + g2*sR[jj][8];
                sG[jj][m*4+3] = g0*r0 + g1*r1 + g2*r2 + gt;
            }
        }
    }
    __syncthreads();

    if (j < 24) {
#pragma unroll
        for (int m = 0; m < 3; ++m) {
            const float tc = sG[j][m*4+0]*sJ[j][0] + sG[j][m*4+1]*sJ[j][1] + sG[j][m*4+2]*sJ[j][2];
            Aw[j*12 + m*4 + 0] = sG[j][m*4+0];
            Aw[j*12 + m*4 + 1] = sG[j][m*4+1];
            Aw[j*12 + m*4 + 2] = sG[j][m*4+2];
            Aw[j*12 + m*4 + 3] = sG[j][m*4+3] - tc;
        }
    }
}

// ---------------------------------------------------------------------------
// Kernel C: fused blend (K=220 GEMM) + skinning.
// Tile: 64 batches x 32 vertices, 256 threads, per-thread 4b x 2v x 3d.
// ---------------------------------------------------------------------------
__global__ __launch_bounds__(256, 2) void k_main(
        const float* __restrict__ shapedirs, const float* __restrict__ posedirs,
        const float* __restrict__ v_template, const float* __restrict__ weights,
        const float* __restrict__ trans,
        const float* __restrict__ ws_coef, const float* __restrict__ ws_A,
        float* __restrict__ out) {
    __shared__ float s_dir[32][172];   // [local v][local_p*3+d], row pad->conflict-free
    __shared__ float s_coef[64][60];   // [local b][local p], 2-way at worst
    __shared__ float s_A[64][52];      // [local b][4 joints * 12]
    __shared__ float s_w[32][25];
    __shared__ float s_vt[32][4];
    __shared__ float s_tr[64][4];

    const int tid = threadIdx.x;
    const int bg  = tid & 15;          // batch lane 0..15
    const int vg  = tid >> 4;          // vertex group 0..15
    const int vbase = blockIdx.x * 32;
    const int bbase = blockIdx.y * 64;

    // one-time staging (covered by first barrier)
    for (int idx = tid; idx < 32*24; idx += 256) {
        const int lv = idx / 24, jj = idx - lv*24;
        const int v = vbase + lv;
        s_w[lv][jj] = (v < VNUM) ? weights[v*JNUM + jj] : 0.f;
    }
    for (int idx = tid; idx < 32*3; idx += 256) {
        const int lv = idx / 3, d = idx - lv*3;
        const int v = vbase + lv;
        s_vt[lv][d] = (v < VNUM) ? v_template[v*3 + d] : 0.f;
    }
    for (int idx = tid; idx < 64*3; idx += 256) {
        const int lb = idx / 3, d = idx - lb*3;
        s_tr[lb][d] = trans[(bbase+lb)*3 + d];
    }

    float vh[4][2][3];
#pragma unroll
    for (int i = 0; i < 4; ++i)
#pragma unroll
        for (int t = 0; t < 2; ++t)
#pragma unroll
            for (int d = 0; d < 3; ++d) vh[i][t][d] = 0.f;

    // ---- K loop: 4 chunks of {56,56,56,52} K-rows ----
#pragma unroll 1
    for (int cc = 0; cc < 4; ++cc) {
        const int pbase = cc*56;
        const int np  = (cc < 3) ? 56 : 52;
        const int nf4 = np >> 2;                 // 14 / 13

        if (cc) __syncthreads();                 // previous compute done
        // stage dirs (transpose p-major global -> v-major LDS)
        for (int idx = tid; idx < np*96; idx += 256) {
            const int lp = idx / 96, f = idx - lp*96;
            const int p = pbase + lp;
            const int gc = vbase*3 + f;
            float val = 0.f;
            if (gc < K3 && p < KTOT)
                val = (p < NBETA) ? shapedirs[p*K3 + gc]
                                  : posedirs[(p-NBETA)*K3 + gc];
            const int lv = f/3, d = f - lv*3;
            s_dir[lv][lp*3 + d] = val;
        }
        // stage coefs
        for (int idx = tid; idx < 64*nf4; idx += 256) {
            const int lb = idx / nf4, q = idx - lb*nf4;
            const float4 v4 = *(const float4*)&ws_coef[(size_t)(bbase+lb)*COEF_ROW + pbase + q*4];
            *(float4*)&s_coef[lb][q*4] = v4;
        }
        __syncthreads();

#pragma unroll 1
        for (int p4 = 0; p4 < nf4; ++p4) {
            float4 cf[4];
#pragma unroll
            for (int i = 0; i < 4; ++i)
                cf[i] = *(const float4*)&s_coef[i*16+bg][p4*4];
#pragma unroll
            for (int t = 0; t < 2; ++t) {
                const float* dr = &s_dir[vg*2+t][p4*12];
                const float4 d0 = *(const float4*)(dr);
                const float4 d1 = *(const float4*)(dr+4);
                const float4 d2 = *(const float4*)(dr+8);
#pragma unroll
                for (int i = 0; i < 4; ++i) {
                    vh[i][t][0] += cf[i].x*d0.x + cf[i].y*d0.w + cf[i].z*d1.z + cf[i].w*d2.y;
                    vh[i][t][1] += cf[i].x*d0.y + cf[i].y*d1.x + cf[i].z*d1.w + cf[i].w*d2.z;
                    vh[i][t][2] += cf[i].x*d0.z + cf[i].y*d1.y + cf[i].z*d2.x + cf[i].w*d2.w;
                }
            }
        }
    }
    __syncthreads();

    // add template
#pragma unroll
    for (int t = 0; t < 2; ++t)
#pragma unroll
        for (int d = 0; d < 3; ++d) {
            const float vt = s_vt[vg*2+t][d];
#pragma unroll
            for (int i = 0; i < 4; ++i) vh[i][t][d] += vt;
        }

    // ---- skinning: out = sum_j w[v][j] * (A_rot . vh + A_t) + trans ----
    float o[4][2][3];
#pragma unroll
    for (int i = 0; i < 4; ++i) {
        const float t0 = s_tr[i*16+bg][0], t1 = s_tr[i*16+bg][1], t2 = s_tr[i*16+bg][2];
#pragma unroll
        for (int t = 0; t < 2; ++t) { o[i][t][0] = t0; o[i][t][1] = t1; o[i][t][2] = t2; }
    }

#pragma unroll 1
    for (int jc = 0; jc < 6; ++jc) {
        // stage 4 joints of A
        for (int idx = tid; idx < 64*12; idx += 256) {
            const int lb = idx / 12, q = idx - lb*12;
            const float4 v4 = *(const float4*)&ws_A[(size_t)(bbase+lb)*A_ROW + jc*48 + q*4];
            *(float4*)&s_A[lb][q*4] = v4;
        }
        __syncthreads();
#pragma unroll
        for (int jl = 0; jl < 4; ++jl) {
            const int jj = jc*4 + jl;
            const float w0 = s_w[vg*2+0][jj];
            const float w1 = s_w[vg*2+1][jj];
#pragma unroll
            for (int i = 0; i < 4; ++i) {
                const float* ar = &s_A[i*16+bg][jl*12];
                const float4 a0 = *(const float4*)(ar);
                const float4 a1 = *(const float4*)(ar+4);
                const float4 a2 = *(const float4*)(ar+8);
                // t = 0
                {
                    const float x = vh[i][0][0], y = vh[i][0][1], z = vh[i][0][2];
                    o[i][0][0] += w0*(a0.w + a0.x*x + a0.y*y + a0.z*z);
                    o[i][0][1] += w0*(a1.w + a1.x*x + a1.y*y + a1.z*z);
                    o[i][0][2] += w0*(a2.w + a2.x*x + a2.y*y + a2.z*z);
                }
                // t = 1
                {
                    const float x = vh[i][1][0], y = vh[i][1][1], z = vh[i][1][2];
                    o[i][1][0] += w1*(a0.w + a0.x*x + a0.y*y + a0.z*z);
                    o[i][1][1] += w1*(a1.w + a1.x*x + a1.y*y + a1.z*z);
                    o[i][1][2] += w1*(a2.w + a2.x*x + a2.y*y + a2.z*z);
                }
            }
        }
        __syncthreads();
    }

    // ---- store ----
#pragma unroll
    for (int t = 0; t < 2; ++t) {
        const int v = vbase + vg*2 + t;
        if (v < VNUM) {
#pragma unroll
            for (int i = 0; i < 4; ++i) {
                const size_t base = ((size_t)(bbase + i*16 + bg)*VNUM + v)*3;
                out[base+0] = o[i][t][0];
                out[base+1] = o[i][t][1];
                out[base+2] = o[i][t][2];
            }
        }
    }
}

// ---------------------------------------------------------------------------
extern "C" void kernel_launch(void* const* d_in, const int* in_sizes, int n_in,
                              void* d_out, int out_size, void* d_ws, size_t ws_size,
                              hipStream_t stream) {
    const float* shapes     = (const float*)d_in[0];
    const float* poses      = (const float*)d_in[1];
    const float* trans      = (const float*)d_in[2];
    const float* v_template = (const float*)d_in[3];
    const float* shapedirs  = (const float*)d_in[4];
    const float* posedirs   = (const float*)d_in[5];
    const float* Jreg       = (const float*)d_in[6];
    const float* weights    = (const float*)d_in[7];
    float* ws  = (float*)d_ws;
    float* out = (float*)d_out;

    k_sj<<<24, 256, 0, stream>>>(v_template, shapedirs, Jreg, ws);
    k_batch<<<1024, 64, 0, stream>>>(shapes, poses, ws);
    k_main<<<dim3((VNUM + 31)/32, BNUM/64), 256, 0, stream>>>(
        shapedirs, posedirs, v_template, weights, trans,
        ws + COEF_OFF, ws + AW_OFF, out);
}

// Round 4
// 243.362 us; speedup vs baseline: 2.2638x; 2.2638x over previous
//
#include <hip/hip_runtime.h>
#include <math.h>

#define VNUM 6890
#define JNUM 24
#define BNUM 1024
#define NBETA 10
#define K3 (3*VNUM)          // 20670
#define KTOT 217             // 10 shape + 207 pose rows
#define KPAD 256             // K padded for MFMA chunks
#define CROWS 20736          // 216 tiles * 96 coord-rows

// ---- workspace layout (float offsets) ----
#define SJ_OFF    0                         // 24*33 fp32 (reserve 1024)
#define COEFB_OFF 1024                      // [1024][256] bf16 = 131072 floats
#define AB_OFF    (COEFB_OFF + 131072)      // [1024][12][32] bf16 = 196608 floats
#define DT_OFF    (AB_OFF + 196608)         // [20736][256] bf16 = 2654208 floats
// total ~2.98M floats ~ 11.4 MB

__constant__ int c_parents[24] = {-1,0,0,0,1,2,3,4,5,6,7,8,9,9,9,12,13,14,16,17,18,19,20,21};

typedef float  f32x4  __attribute__((ext_vector_type(4)));
typedef short  bf16x8 __attribute__((ext_vector_type(8)));
#define MFMA16(a,b,c) __builtin_amdgcn_mfma_f32_16x16x32_bf16((a),(b),(c),0,0,0)

__device__ __forceinline__ unsigned short f2bf(float f) {
    union { float f; unsigned int u; } v; v.f = f;
    unsigned int u = v.u;
    u += 0x7fffu + ((u >> 16) & 1u);
    return (unsigned short)(u >> 16);
}

// ---------------------------------------------------------------------------
// k_tr: build dirsT[c][k] bf16 (k-contiguous rows of 256), zero-padded.
// ---------------------------------------------------------------------------
__global__ __launch_bounds__(256) void k_tr(const float* __restrict__ shapedirs,
                                            const float* __restrict__ posedirs,
                                            unsigned short* __restrict__ dirsT) {
    __shared__ float st[64][65];
    const int tid = threadIdx.x;
    const int cbase = blockIdx.x * 64, kbase = blockIdx.y * 64;
#pragma unroll
    for (int i = 0; i < 16; ++i) {
        int f = tid + i*256;
        int kl = f >> 6, cl = f & 63;
        int k = kbase + kl, c = cbase + cl;
        float v = 0.f;
        if (c < K3 && k < KTOT)
            v = (k < NBETA) ? shapedirs[(size_t)k*K3 + c]
                            : posedirs[(size_t)(k-NBETA)*K3 + c];
        st[kl][cl] = v;
    }
    __syncthreads();
#pragma unroll
    for (int i = 0; i < 16; ++i) {
        int f = tid + i*256;
        int cl = f >> 6, kl = f & 63;
        int c = cbase + cl;
        if (c < CROWS)
            dirsT[(size_t)c*KPAD + kbase + kl] = f2bf(st[kl][cl]);
    }
}

// ---------------------------------------------------------------------------
// k_sj: SJ[j][k][d] = sum_v dirs[k][v*3+d] * Jreg[v][j]  (k=10 -> v_template)
// ---------------------------------------------------------------------------
__global__ __launch_bounds__(256) void k_sj(const float* __restrict__ v_template,
                                            const float* __restrict__ shapedirs,
                                            const float* __restrict__ Jreg,
                                            float* __restrict__ ws) {
    const int j = blockIdx.x;
    const int tid = threadIdx.x;
    float acc[33];
#pragma unroll
    for (int i = 0; i < 33; ++i) acc[i] = 0.f;
    for (int v = tid; v < VNUM; v += 256) {
        const float jr = Jreg[v*JNUM + j];
#pragma unroll
        for (int d = 0; d < 3; ++d) acc[30+d] += v_template[v*3+d] * jr;
#pragma unroll
        for (int k = 0; k < NBETA; ++k)
#pragma unroll
            for (int d = 0; d < 3; ++d)
                acc[k*3+d] += shapedirs[k*K3 + v*3 + d] * jr;
    }
#pragma unroll
    for (int i = 0; i < 33; ++i)
        for (int off = 32; off > 0; off >>= 1)
            acc[i] += __shfl_down(acc[i], off, 64);
    __shared__ float red[4][33];
    const int lane = tid & 63, wv = tid >> 6;
    if (lane == 0) {
#pragma unroll
        for (int i = 0; i < 33; ++i) red[wv][i] = acc[i];
    }
    __syncthreads();
    if (tid < 33)
        ws[SJ_OFF + j*33 + tid] = red[0][tid] + red[1][tid] + red[2][tid] + red[3][tid];
}

// ---------------------------------------------------------------------------
// k_batch: Rodrigues, joints, chain; writes bf16 coef row [256] and
// A as bf16 [b][mn=12][j=32] (j-contiguous, padded with zeros).
// ---------------------------------------------------------------------------
__global__ __launch_bounds__(64) void k_batch(const float* __restrict__ shapes,
                                              const float* __restrict__ poses,
                                              float* __restrict__ ws) {
    const int b = blockIdx.x;
    const int j = threadIdx.x;
    __shared__ float sR[24][9];
    __shared__ float sJ[24][3];
    __shared__ float sG[24][12];

    unsigned short* coefB = (unsigned short*)(ws + COEFB_OFF) + (size_t)b*KPAD;
    unsigned short* Ab    = (unsigned short*)(ws + AB_OFF)    + (size_t)b*384;
    const float* SJ = ws + SJ_OFF;

    if (j < 24) {
        const float rx = poses[b*72 + j*3 + 0];
        const float ry = poses[b*72 + j*3 + 1];
        const float rz = poses[b*72 + j*3 + 2];
        const float t2 = rx*rx + ry*ry + rz*rz + 1e-8f;
        const float th = sqrtf(t2);
        const float iv = 1.f/th;
        const float ax = rx*iv, ay = ry*iv, az = rz*iv;
        const float s = sinf(th), c = cosf(th), o = 1.f - c;
        float K[9] = {0.f, -az, ay,  az, 0.f, -ax,  -ay, ax, 0.f};
        float R[9];
#pragma unroll
        for (int m = 0; m < 3; ++m)
#pragma unroll
            for (int n = 0; n < 3; ++n) {
                const float kk = K[m*3+0]*K[0+n] + K[m*3+1]*K[3+n] + K[m*3+2]*K[6+n];
                R[m*3+n] = ((m==n)?1.f:0.f) + s*K[m*3+n] + o*kk;
            }
#pragma unroll
        for (int e = 0; e < 9; ++e) sR[j][e] = R[e];
        if (j >= 1) {
#pragma unroll
            for (int e = 0; e < 9; ++e)
                coefB[10 + (j-1)*9 + e] = f2bf(R[e] - ((e==0||e==4||e==8)?1.f:0.f));
        }
#pragma unroll
        for (int d = 0; d < 3; ++d) {
            float jl = SJ[j*33 + 30 + d];
#pragma unroll
            for (int k = 0; k < NBETA; ++k) jl += shapes[b*NBETA+k] * SJ[j*33 + k*3 + d];
            sJ[j][d] = jl;
        }
    }
    if (j < NBETA) coefB[j] = f2bf(shapes[b*NBETA + j]);
    if (j >= 24 && j < 63) coefB[KTOT + (j-24)] = 0;   // pad 217..255
    __syncthreads();

    if (j == 0) {
#pragma unroll
        for (int m = 0; m < 3; ++m) {
            sG[0][m*4+0] = sR[0][m*3+0];
            sG[0][m*4+1] = sR[0][m*3+1];
            sG[0][m*4+2] = sR[0][m*3+2];
            sG[0][m*4+3] = sJ[0][m];
        }
        for (int jj = 1; jj < 24; ++jj) {
            const int p = c_parents[jj];
            const float r0 = sJ[jj][0]-sJ[p][0];
            const float r1 = sJ[jj][1]-sJ[p][1];
            const float r2 = sJ[jj][2]-sJ[p][2];
            for (int m = 0; m < 3; ++m) {
                const float g0 = sG[p][m*4+0], g1 = sG[p][m*4+1], g2 = sG[p][m*4+2], gt = sG[p][m*4+3];
                sG[jj][m*4+0] = g0*sR[jj][0] + g1*sR[jj][3] + g2*sR[jj][6];
                sG[jj][m*4+1] = g0*sR[jj][1] + g1*sR[jj][4] + g2*sR[jj][7];
                sG[jj][m*4+2] = g0*sR[jj][2] + g1*sR[jj][5] + g2*sR[jj][8];
                sG[jj][m*4+3] = g0*r0 + g1*r1 + g2*r2 + gt;
            }
        }
    }
    __syncthreads();

    if (j < 24) {
#pragma unroll
        for (int m = 0; m < 3; ++m) {
            const float tc = sG[j][m*4+0]*sJ[j][0] + sG[j][m*4+1]*sJ[j][1] + sG[j][m*4+2]*sJ[j][2];
#pragma unroll
            for (int n = 0; n < 3; ++n)
                Ab[(m*4+n)*32 + j] = f2bf(sG[j][m*4+n]);
            Ab[(m*4+3)*32 + j] = f2bf(sG[j][m*4+3] - tc);
        }
    } else if (j < 32) {
#pragma unroll
        for (int mn = 0; mn < 12; ++mn) Ab[mn*32 + j] = 0;
    }
}

// ---------------------------------------------------------------------------
// k_main: fused MFMA blend-GEMM + MFMA skinning.
// Tile 64 batches x 32 vertices (96 coords), 256 threads = 4 waves.
// ---------------------------------------------------------------------------
#define LM_COEF 0            // u16 [64][72]  = 9216 B   (phase A)   } union
#define LM_DIRS 9216         // u16 [96][72]  = 13824 B  (phase A)   } with
#define LM_OUT  0            // f32 [64][97]  = 24832 B  (phase D/E) } s_out
#define LM_VH   24832        // f32 [64][97]  = 24832 B
#define LM_A    49664        // u16 [64][392] = 50176 B
#define LM_W    99840        // u16 [32][40]  = 2560 B
#define LM_VT   102400       // f32 [96]      = 384 B
#define LM_TR   102784       // f32 [64*3]    = 768 B
#define LM_SIZE 103552

__global__ __launch_bounds__(256, 1) void k_main(
        const unsigned short* __restrict__ dirsT,
        const unsigned short* __restrict__ coefB,
        const unsigned short* __restrict__ Ab,
        const float* __restrict__ v_template,
        const float* __restrict__ weights,
        const float* __restrict__ trans,
        float* __restrict__ out) {
    __shared__ __align__(16) unsigned char sm[LM_SIZE];
    unsigned short* s_coef = (unsigned short*)(sm + LM_COEF);
    unsigned short* s_dirs = (unsigned short*)(sm + LM_DIRS);
    float*          s_out  = (float*)(sm + LM_OUT);
    float*          s_vh   = (float*)(sm + LM_VH);
    unsigned short* s_A    = (unsigned short*)(sm + LM_A);
    unsigned short* s_w    = (unsigned short*)(sm + LM_W);
    float*          s_vt   = (float*)(sm + LM_VT);
    float*          s_tr   = (float*)(sm + LM_TR);

    const int tid = threadIdx.x;
    const int w   = tid >> 6;
    const int l   = tid & 63;
    const int lm  = l & 15;
    const int g8  = (l >> 4) * 8;
    const int vbase = blockIdx.x * 32;
    const int c0    = blockIdx.x * 96;
    const int bbase = blockIdx.y * 64;

    // ---- one-time stage: s_A, s_w, s_vt, s_tr ----
#pragma unroll
    for (int i = 0; i < 12; ++i) {
        int f = tid + i*256;
        int b = f / 48, q = f - b*48;
        uint4 v = *(const uint4*)(Ab + (size_t)(bbase+b)*384 + q*8);
        *(uint4*)(s_A + b*392 + q*8) = v;
    }
#pragma unroll
    for (int i = 0; i < 4; ++i) {
        int f = tid + i*256;
        int vv = f >> 5, jj = f & 31;
        int gv = vbase + vv;
        float val = (jj < 24 && gv < VNUM) ? weights[(size_t)gv*JNUM + jj] : 0.f;
        s_w[vv*40 + jj] = f2bf(val);
    }
    if (tid < 96) {
        int gc = c0 + tid;
        s_vt[tid] = (gc < K3) ? v_template[gc] : 0.f;
    }
    if (tid < 192) s_tr[tid] = trans[bbase*3 + tid];

    // ---- Phase A: vh = coef @ dirs^T   (M=64 b, N=96 c, K=256 in 4 chunks) ----
    const f32x4 fz = {0.f, 0.f, 0.f, 0.f};
    f32x4 acc[6];
#pragma unroll
    for (int i = 0; i < 6; ++i) acc[i] = fz;

#pragma unroll 1
    for (int kc = 0; kc < 4; ++kc) {
        if (kc) __syncthreads();
#pragma unroll
        for (int i = 0; i < 2; ++i) {
            int f = tid + i*256;
            int b = f >> 3, q = f & 7;
            uint4 v = *(const uint4*)(coefB + (((size_t)(bbase+b))<<8) + kc*64 + q*8);
            *(uint4*)(s_coef + b*72 + q*8) = v;
        }
#pragma unroll
        for (int i = 0; i < 3; ++i) {
            int f = tid + i*256;
            int cl = f >> 3, q = f & 7;
            uint4 v = *(const uint4*)(dirsT + (((size_t)(c0+cl))<<8) + kc*64 + q*8);
            *(uint4*)(s_dirs + cl*72 + q*8) = v;
        }
        __syncthreads();
#pragma unroll
        for (int s = 0; s < 2; ++s) {
            bf16x8 af = *(const bf16x8*)(s_coef + (w*16 + lm)*72 + s*32 + g8);
#pragma unroll
            for (int cf = 0; cf < 6; ++cf) {
                bf16x8 bfv = *(const bf16x8*)(s_dirs + (cf*16 + lm)*72 + s*32 + g8);
                acc[cf] = MFMA16(af, bfv, acc[cf]);
            }
        }
    }

    // ---- Phase B: vh += template -> LDS ----
#pragma unroll
    for (int cf = 0; cf < 6; ++cf) {
        int col = cf*16 + lm;
        float vtv = s_vt[col];
#pragma unroll
        for (int r = 0; r < 4; ++r) {
            int row = w*16 + (l>>4)*4 + r;
            s_vh[row*97 + col] = acc[cf][r] + vtv;
        }
    }
    __syncthreads();

    // ---- Phase C: T_mn[v][b] = w[v][j] @ A[j][b]  (M=32, N=64, K=32) ----
    bf16x8 a0 = *(const bf16x8*)(s_w + lm*40 + g8);
    bf16x8 a1 = *(const bf16x8*)(s_w + (16 + lm)*40 + g8);
    f32x4 T0[12], T1[12];
#pragma unroll
    for (int mn = 0; mn < 12; ++mn) { T0[mn] = fz; T1[mn] = fz; }
#pragma unroll
    for (int mn = 0; mn < 12; ++mn) {
        bf16x8 bfv = *(const bf16x8*)(s_A + (w*16 + lm)*392 + mn*32 + g8);
        T0[mn] = MFMA16(a0, bfv, T0[mn]);
        T1[mn] = MFMA16(a1, bfv, T1[mn]);
    }

    // ---- Phase D: out = T . (vh,1) + trans  (fp32 epilogue) ----
    {
        const int b = w*16 + lm;
        const float tr0 = s_tr[b*3+0], tr1 = s_tr[b*3+1], tr2 = s_tr[b*3+2];
#pragma unroll
        for (int mf = 0; mf < 2; ++mf) {
#pragma unroll
            for (int r = 0; r < 4; ++r) {
                const int vl = mf*16 + (l>>4)*4 + r;
                const float x = s_vh[b*97 + vl*3 + 0];
                const float y = s_vh[b*97 + vl*3 + 1];
                const float z = s_vh[b*97 + vl*3 + 2];
                float t[12];
#pragma unroll
                for (int mn = 0; mn < 12; ++mn) t[mn] = mf ? T1[mn][r] : T0[mn][r];
                const float o0 = t[3]  + t[0]*x + t[1]*y + t[2]*z  + tr0;
                const float o1 = t[7]  + t[4]*x + t[5]*y + t[6]*z  + tr1;
                const float o2 = t[11] + t[8]*x + t[9]*y + t[10]*z + tr2;
                s_out[b*97 + vl*3 + 0] = o0;
                s_out[b*97 + vl*3 + 1] = o1;
                s_out[b*97 + vl*3 + 2] = o2;
            }
        }
    }
    __syncthreads();

    // ---- Phase E: coalesced store ----
#pragma unroll
    for (int i = 0; i < 24; ++i) {
        int f = tid + i*256;
        int b = f / 96, col = f - b*96;
        int gc = c0 + col;
        if (gc < K3)
            out[(size_t)(bbase+b)*K3 + gc] = s_out[b*97 + col];
    }
}

// ---------------------------------------------------------------------------
extern "C" void kernel_launch(void* const* d_in, const int* in_sizes, int n_in,
                              void* d_out, int out_size, void* d_ws, size_t ws_size,
                              hipStream_t stream) {
    const float* shapes     = (const float*)d_in[0];
    const float* poses      = (const float*)d_in[1];
    const float* trans      = (const float*)d_in[2];
    const float* v_template = (const float*)d_in[3];
    const float* shapedirs  = (const float*)d_in[4];
    const float* posedirs   = (const float*)d_in[5];
    const float* Jreg       = (const float*)d_in[6];
    const float* weights    = (const float*)d_in[7];
    float* ws  = (float*)d_ws;
    float* out = (float*)d_out;

    unsigned short* dirsT = (unsigned short*)(ws + DT_OFF);
    unsigned short* coefB = (unsigned short*)(ws + COEFB_OFF);
    unsigned short* Ab    = (unsigned short*)(ws + AB_OFF);

    k_tr<<<dim3(CROWS/64, KPAD/64), 256, 0, stream>>>(shapedirs, posedirs, dirsT);
    k_sj<<<24, 256, 0, stream>>>(v_template, shapedirs, Jreg, ws);
    k_batch<<<1024, 64, 0, stream>>>(shapes, poses, ws);
    k_main<<<dim3((VNUM + 31)/32, BNUM/64), 256, 0, stream>>>(
        dirsT, coefB, Ab, v_template, weights, trans, out);
}

// Round 8
// 202.440 us; speedup vs baseline: 2.7214x; 1.2021x over previous
//
#include <hip/hip_runtime.h>
#include <math.h>

#define VNUM 6890
#define JNUM 24
#define BNUM 1024
#define NBETA 10
#define K3 (3*VNUM)          // 20670
#define KTOT 217             // 10 shape + 207 pose rows
#define KPAD 256             // K padded for MFMA chunks
#define CROWS 20736          // 216 tiles * 96 coord-rows

// ---- workspace layout (float offsets) ----
#define SJ_OFF    0                         // 24*33 fp32 (reserve 1024)
#define COEFB_OFF 1024                      // [1024][256] bf16 = 131072 floats
#define AB_OFF    (COEFB_OFF + 131072)      // [1024][12][32] bf16 = 196608 floats
#define DT_OFF    (AB_OFF + 196608)         // [20736][256] bf16 = 2654208 floats

__constant__ int c_parents[24] = {-1,0,0,0,1,2,3,4,5,6,7,8,9,9,9,12,13,14,16,17,18,19,20,21};

typedef float  f32x4  __attribute__((ext_vector_type(4)));
typedef short  bf16x8 __attribute__((ext_vector_type(8)));
#define MFMA16(a,b,c) __builtin_amdgcn_mfma_f32_16x16x32_bf16((a),(b),(c),0,0,0)

__device__ __forceinline__ unsigned short f2bf(float f) {
    union { float f; unsigned int u; } v; v.f = f;
    unsigned int u = v.u;
    u += 0x7fffu + ((u >> 16) & 1u);
    return (unsigned short)(u >> 16);
}

// ---------------------------------------------------------------------------
// k_tr: build dirsT[c][k] bf16 (k-contiguous rows of 256), zero-padded.
// (round-4 verified, byte-identical)
// ---------------------------------------------------------------------------
__global__ __launch_bounds__(256) void k_tr(const float* __restrict__ shapedirs,
                                            const float* __restrict__ posedirs,
                                            unsigned short* __restrict__ dirsT) {
    __shared__ float st[64][65];
    const int tid = threadIdx.x;
    const int cbase = blockIdx.x * 64, kbase = blockIdx.y * 64;
#pragma unroll
    for (int i = 0; i < 16; ++i) {
        int f = tid + i*256;
        int kl = f >> 6, cl = f & 63;
        int k = kbase + kl, c = cbase + cl;
        float v = 0.f;
        if (c < K3 && k < KTOT)
            v = (k < NBETA) ? shapedirs[(size_t)k*K3 + c]
                            : posedirs[(size_t)(k-NBETA)*K3 + c];
        st[kl][cl] = v;
    }
    __syncthreads();
#pragma unroll
    for (int i = 0; i < 16; ++i) {
        int f = tid + i*256;
        int cl = f >> 6, kl = f & 63;
        int c = cbase + cl;
        if (c < CROWS)
            dirsT[(size_t)c*KPAD + kbase + kl] = f2bf(st[kl][cl]);
    }
}

// ---------------------------------------------------------------------------
// k_sj: monolithic per-joint reduction (round-4 verified, byte-identical).
// ---------------------------------------------------------------------------
__global__ __launch_bounds__(256) void k_sj(const float* __restrict__ v_template,
                                            const float* __restrict__ shapedirs,
                                            const float* __restrict__ Jreg,
                                            float* __restrict__ ws) {
    const int j = blockIdx.x;
    const int tid = threadIdx.x;
    float acc[33];
#pragma unroll
    for (int i = 0; i < 33; ++i) acc[i] = 0.f;
    for (int v = tid; v < VNUM; v += 256) {
        const float jr = Jreg[v*JNUM + j];
#pragma unroll
        for (int d = 0; d < 3; ++d) acc[30+d] += v_template[v*3+d] * jr;
#pragma unroll
        for (int k = 0; k < NBETA; ++k)
#pragma unroll
            for (int d = 0; d < 3; ++d)
                acc[k*3+d] += shapedirs[k*K3 + v*3 + d] * jr;
    }
#pragma unroll
    for (int i = 0; i < 33; ++i)
        for (int off = 32; off > 0; off >>= 1)
            acc[i] += __shfl_down(acc[i], off, 64);
    __shared__ float red[4][33];
    const int lane = tid & 63, wv = tid >> 6;
    if (lane == 0) {
#pragma unroll
        for (int i = 0; i < 33; ++i) red[wv][i] = acc[i];
    }
    __syncthreads();
    if (tid < 33)
        ws[SJ_OFF + j*33 + tid] = red[0][tid] + red[1][tid] + red[2][tid] + red[3][tid];
}

// ---------------------------------------------------------------------------
// k_batch: Rodrigues, joints, chain (round-4 verified, byte-identical).
// ---------------------------------------------------------------------------
__global__ __launch_bounds__(64) void k_batch(const float* __restrict__ shapes,
                                              const float* __restrict__ poses,
                                              float* __restrict__ ws) {
    const int b = blockIdx.x;
    const int j = threadIdx.x;
    __shared__ float sR[24][9];
    __shared__ float sJ[24][3];
    __shared__ float sG[24][12];

    unsigned short* coefB = (unsigned short*)(ws + COEFB_OFF) + (size_t)b*KPAD;
    unsigned short* Ab    = (unsigned short*)(ws + AB_OFF)    + (size_t)b*384;
    const float* SJ = ws + SJ_OFF;

    if (j < 24) {
        const float rx = poses[b*72 + j*3 + 0];
        const float ry = poses[b*72 + j*3 + 1];
        const float rz = poses[b*72 + j*3 + 2];
        const float t2 = rx*rx + ry*ry + rz*rz + 1e-8f;
        const float th = sqrtf(t2);
        const float iv = 1.f/th;
        const float ax = rx*iv, ay = ry*iv, az = rz*iv;
        const float s = sinf(th), c = cosf(th), o = 1.f - c;
        float K[9] = {0.f, -az, ay,  az, 0.f, -ax,  -ay, ax, 0.f};
        float R[9];
#pragma unroll
        for (int m = 0; m < 3; ++m)
#pragma unroll
            for (int n = 0; n < 3; ++n) {
                const float kk = K[m*3+0]*K[0+n] + K[m*3+1]*K[3+n] + K[m*3+2]*K[6+n];
                R[m*3+n] = ((m==n)?1.f:0.f) + s*K[m*3+n] + o*kk;
            }
#pragma unroll
        for (int e = 0; e < 9; ++e) sR[j][e] = R[e];
        if (j >= 1) {
#pragma unroll
            for (int e = 0; e < 9; ++e)
                coefB[10 + (j-1)*9 + e] = f2bf(R[e] - ((e==0||e==4||e==8)?1.f:0.f));
        }
#pragma unroll
        for (int d = 0; d < 3; ++d) {
            float jl = SJ[j*33 + 30 + d];
#pragma unroll
            for (int k = 0; k < NBETA; ++k) jl += shapes[b*NBETA+k] * SJ[j*33 + k*3 + d];
            sJ[j][d] = jl;
        }
    }
    if (j < NBETA) coefB[j] = f2bf(shapes[b*NBETA + j]);
    if (j >= 24 && j < 63) coefB[KTOT + (j-24)] = 0;   // pad 217..255
    __syncthreads();

    if (j == 0) {
#pragma unroll
        for (int m = 0; m < 3; ++m) {
            sG[0][m*4+0] = sR[0][m*3+0];
            sG[0][m*4+1] = sR[0][m*3+1];
            sG[0][m*4+2] = sR[0][m*3+2];
            sG[0][m*4+3] = sJ[0][m];
        }
        for (int jj = 1; jj < 24; ++jj) {
            const int p = c_parents[jj];
            const float r0 = sJ[jj][0]-sJ[p][0];
            const float r1 = sJ[jj][1]-sJ[p][1];
            const float r2 = sJ[jj][2]-sJ[p][2];
            for (int m = 0; m < 3; ++m) {
                const float g0 = sG[p][m*4+0], g1 = sG[p][m*4+1], g2 = sG[p][m*4+2], gt = sG[p][m*4+3];
                sG[jj][m*4+0] = g0*sR[jj][0] + g1*sR[jj][3] + g2*sR[jj][6];
                sG[jj][m*4+1] = g0*sR[jj][1] + g1*sR[jj][4] + g2*sR[jj][7];
                sG[jj][m*4+2] = g0*sR[jj][2] + g1*sR[jj][5] + g2*sR[jj][8];
                sG[jj][m*4+3] = g0*r0 + g1*r1 + g2*r2 + gt;
            }
        }
    }
    __syncthreads();

    if (j < 24) {
#pragma unroll
        for (int m = 0; m < 3; ++m) {
            const float tc = sG[j][m*4+0]*sJ[j][0] + sG[j][m*4+1]*sJ[j][1] + sG[j][m*4+2]*sJ[j][2];
#pragma unroll
            for (int n = 0; n < 3; ++n)
                Ab[(m*4+n)*32 + j] = f2bf(sG[j][m*4+n]);
            Ab[(m*4+3)*32 + j] = f2bf(sG[j][m*4+3] - tc);
        }
    } else if (j < 32) {
#pragma unroll
        for (int mn = 0; mn < 12; ++mn) Ab[mn*32 + j] = 0;
    }
}

// ---------------------------------------------------------------------------
// k_main: round-4 kernel with EXACTLY ONE delta: s_A LDS staging removed,
// skinning B-fragments read direct from global Ab (identical addresses).
// LDS 103552 -> 53376 B => 3 blocks/CU.
// ---------------------------------------------------------------------------
#define LM_COEF 0            // u16 [64][72]  = 9216 B   (phase A)   } union
#define LM_DIRS 9216         // u16 [96][72]  = 13824 B  (phase A)   } with
#define LM_OUT  0            // f32 [64][97]  = 24832 B  (phase D/E) } s_out
#define LM_VH   24832        // f32 [64][97]  = 24832 B
#define LM_W    49664        // u16 [32][40]  = 2560 B
#define LM_VT   52224        // f32 [96]      = 384 B
#define LM_TR   52608        // f32 [64*3]    = 768 B
#define LM_SIZE 53376

__global__ __launch_bounds__(256, 3) void k_main(
        const unsigned short* __restrict__ dirsT,
        const unsigned short* __restrict__ coefB,
        const unsigned short* __restrict__ Ab,
        const float* __restrict__ v_template,
        const float* __restrict__ weights,
        const float* __restrict__ trans,
        float* __restrict__ out) {
    __shared__ __align__(16) unsigned char sm[LM_SIZE];
    unsigned short* s_coef = (unsigned short*)(sm + LM_COEF);
    unsigned short* s_dirs = (unsigned short*)(sm + LM_DIRS);
    float*          s_out  = (float*)(sm + LM_OUT);
    float*          s_vh   = (float*)(sm + LM_VH);
    unsigned short* s_w    = (unsigned short*)(sm + LM_W);
    float*          s_vt   = (float*)(sm + LM_VT);
    float*          s_tr   = (float*)(sm + LM_TR);

    const int tid = threadIdx.x;
    const int w   = tid >> 6;
    const int l   = tid & 63;
    const int lm  = l & 15;
    const int g8  = (l >> 4) * 8;
    const int vbase = blockIdx.x * 32;
    const int c0    = blockIdx.x * 96;
    const int bbase = blockIdx.y * 64;

    // ---- one-time stage: s_w, s_vt, s_tr ----
#pragma unroll
    for (int i = 0; i < 4; ++i) {
        int f = tid + i*256;
        int vv = f >> 5, jj = f & 31;
        int gv = vbase + vv;
        float val = (jj < 24 && gv < VNUM) ? weights[(size_t)gv*JNUM + jj] : 0.f;
        s_w[vv*40 + jj] = f2bf(val);
    }
    if (tid < 96) {
        int gc = c0 + tid;
        s_vt[tid] = (gc < K3) ? v_template[gc] : 0.f;
    }
    if (tid < 192) s_tr[tid] = trans[bbase*3 + tid];

    // ---- Phase A: vh = coef @ dirs^T   (M=64 b, N=96 c, K=256 in 4 chunks) ----
    const f32x4 fz = {0.f, 0.f, 0.f, 0.f};
    f32x4 acc[6];
#pragma unroll
    for (int i = 0; i < 6; ++i) acc[i] = fz;

#pragma unroll 1
    for (int kc = 0; kc < 4; ++kc) {
        if (kc) __syncthreads();
#pragma unroll
        for (int i = 0; i < 2; ++i) {
            int f = tid + i*256;
            int b = f >> 3, q = f & 7;
            uint4 v = *(const uint4*)(coefB + (((size_t)(bbase+b))<<8) + kc*64 + q*8);
            *(uint4*)(s_coef + b*72 + q*8) = v;
        }
#pragma unroll
        for (int i = 0; i < 3; ++i) {
            int f = tid + i*256;
            int cl = f >> 3, q = f & 7;
            uint4 v = *(const uint4*)(dirsT + (((size_t)(c0+cl))<<8) + kc*64 + q*8);
            *(uint4*)(s_dirs + cl*72 + q*8) = v;
        }
        __syncthreads();
#pragma unroll
        for (int s = 0; s < 2; ++s) {
            bf16x8 af = *(const bf16x8*)(s_coef + (w*16 + lm)*72 + s*32 + g8);
#pragma unroll
            for (int cf = 0; cf < 6; ++cf) {
                bf16x8 bfv = *(const bf16x8*)(s_dirs + (cf*16 + lm)*72 + s*32 + g8);
                acc[cf] = MFMA16(af, bfv, acc[cf]);
            }
        }
    }

    // ---- Phase B: vh += template -> LDS ----
#pragma unroll
    for (int cf = 0; cf < 6; ++cf) {
        int col = cf*16 + lm;
        float vtv = s_vt[col];
#pragma unroll
        for (int r = 0; r < 4; ++r) {
            int row = w*16 + (l>>4)*4 + r;
            s_vh[row*97 + col] = acc[cf][r] + vtv;
        }
    }
    __syncthreads();

    // ---- Phase C: T_mn[v][b] = w[v][j] @ A[j][b]  (M=32, N=64, K=32) ----
    // DELTA vs round 4: B-fragment read direct from global Ab (same addresses
    // as the former s_A staging: s_A[b][q] == Ab[(bbase+b)*384 + q]).
    bf16x8 a0 = *(const bf16x8*)(s_w + lm*40 + g8);
    bf16x8 a1 = *(const bf16x8*)(s_w + (16 + lm)*40 + g8);
    f32x4 T0[12], T1[12];
#pragma unroll
    for (int mn = 0; mn < 12; ++mn) { T0[mn] = fz; T1[mn] = fz; }
    {
        const unsigned short* ab = Ab + (size_t)(bbase + w*16 + lm)*384;
#pragma unroll
        for (int mn = 0; mn < 12; ++mn) {
            bf16x8 bfv = *(const bf16x8*)(ab + mn*32 + g8);
            T0[mn] = MFMA16(a0, bfv, T0[mn]);
            T1[mn] = MFMA16(a1, bfv, T1[mn]);
        }
    }

    // ---- Phase D: out = T . (vh,1) + trans  (fp32 epilogue) ----
    {
        const int b = w*16 + lm;
        const float tr0 = s_tr[b*3+0], tr1 = s_tr[b*3+1], tr2 = s_tr[b*3+2];
#pragma unroll
        for (int mf = 0; mf < 2; ++mf) {
#pragma unroll
            for (int r = 0; r < 4; ++r) {
                const int vl = mf*16 + (l>>4)*4 + r;
                const float x = s_vh[b*97 + vl*3 + 0];
                const float y = s_vh[b*97 + vl*3 + 1];
                const float z = s_vh[b*97 + vl*3 + 2];
                float t[12];
#pragma unroll
                for (int mn = 0; mn < 12; ++mn) t[mn] = mf ? T1[mn][r] : T0[mn][r];
                const float o0 = t[3]  + t[0]*x + t[1]*y + t[2]*z  + tr0;
                const float o1 = t[7]  + t[4]*x + t[5]*y + t[6]*z  + tr1;
                const float o2 = t[11] + t[8]*x + t[9]*y + t[10]*z + tr2;
                s_out[b*97 + vl*3 + 0] = o0;
                s_out[b*97 + vl*3 + 1] = o1;
                s_out[b*97 + vl*3 + 2] = o2;
            }
        }
    }
    __syncthreads();

    // ---- Phase E: coalesced store ----
#pragma unroll
    for (int i = 0; i < 24; ++i) {
        int f = tid + i*256;
        int b = f / 96, col = f - b*96;
        int gc = c0 + col;
        if (gc < K3)
            out[(size_t)(bbase+b)*K3 + gc] = s_out[b*97 + col];
    }
}

// ---------------------------------------------------------------------------
extern "C" void kernel_launch(void* const* d_in, const int* in_sizes, int n_in,
                              void* d_out, int out_size, void* d_ws, size_t ws_size,
                              hipStream_t stream) {
    const float* shapes     = (const float*)d_in[0];
    const float* poses      = (const float*)d_in[1];
    const float* trans      = (const float*)d_in[2];
    const float* v_template = (const float*)d_in[3];
    const float* shapedirs  = (const float*)d_in[4];
    const float* posedirs   = (const float*)d_in[5];
    const float* Jreg       = (const float*)d_in[6];
    const float* weights    = (const float*)d_in[7];
    float* ws  = (float*)d_ws;
    float* out = (float*)d_out;

    unsigned short* dirsT = (unsigned short*)(ws + DT_OFF);
    unsigned short* coefB = (unsigned short*)(ws + COEFB_OFF);
    unsigned short* Ab    = (unsigned short*)(ws + AB_OFF);

    k_tr<<<dim3(CROWS/64, KPAD/64), 256, 0, stream>>>(shapedirs, posedirs, dirsT);
    k_sj<<<24, 256, 0, stream>>>(v_template, shapedirs, Jreg, ws);
    k_batch<<<1024, 64, 0, stream>>>(shapes, poses, ws);
    k_main<<<dim3((VNUM + 31)/32, BNUM/64), 256, 0, stream>>>(
        dirsT, coefB, Ab, v_template, weights, trans, out);
}